// Round 1
// baseline (212.939 us; speedup 1.0000x reference)
//
#include <hip/hip_runtime.h>
#include <math.h>

#define BATCH    64
#define IN_CAPS  2048
#define IN_DIM   16
#define NUM_CAPS 32
#define DIM_CAPS 16
#define NROUTE   3
#define CAPS_EPS 1e-7f

// ---------------------------------------------------------------------------
// Kernel A: hat[b][j][i][m] = sum_n W[i][j][n][m] * x[b][i][n]
// grid 1024 = 128 i-groups x 8 j-groups; 256 threads = 4 waves (wave w -> j)
// Each lane holds W[i, j, :, m0:m0+4] in 16 float4 regs; loops all 64 b.
// ---------------------------------------------------------------------------
__global__ __launch_bounds__(256) void caps_hat_kernel(
    const float* __restrict__ x, const float* __restrict__ W,
    float* __restrict__ hat)
{
  const int bid   = blockIdx.x;
  const int ig    = bid & 127;     // i-group of 16
  const int jb    = bid >> 7;      // 0..7
  const int t     = threadIdx.x;
  const int wv    = t >> 6;        // wave 0..3
  const int l     = t & 63;
  const int j     = jb * 4 + wv;
  const int i_loc = l >> 2;
  const int m0    = (l & 3) * 4;
  const int i     = ig * 16 + i_loc;

  float4 Wr[16];
  {
    const float* wbase = W + (((size_t)i * NUM_CAPS + j) * IN_DIM) * DIM_CAPS + m0;
#pragma unroll
    for (int n = 0; n < 16; ++n)
      Wr[n] = *reinterpret_cast<const float4*>(wbase + n * DIM_CAPS);
  }

  __shared__ float xs[16][16][17];   // [b_loc][i_loc][n], pad 17: conflict-free

  for (int bc = 0; bc < 4; ++bc) {
    const int b0 = bc * 16;
    // stage x[b0..b0+15][ig*16..+15][:]  (16 KB, 1024 float4 / 256 threads)
#pragma unroll
    for (int k = 0; k < 4; ++k) {
      const int u   = t + k * 256;
      const int bl  = u >> 6;
      const int rem = u & 63;
      const int il  = rem >> 2;
      const int n0  = (rem & 3) * 4;
      float4 v = *reinterpret_cast<const float4*>(
          x + ((size_t)(b0 + bl) * IN_CAPS + ig * 16 + il) * IN_DIM + n0);
      xs[bl][il][n0 + 0] = v.x;
      xs[bl][il][n0 + 1] = v.y;
      xs[bl][il][n0 + 2] = v.z;
      xs[bl][il][n0 + 3] = v.w;
    }
    __syncthreads();
#pragma unroll
    for (int bl = 0; bl < 16; ++bl) {
      const int b = b0 + bl;
      float4 acc = make_float4(0.f, 0.f, 0.f, 0.f);
#pragma unroll
      for (int n = 0; n < 16; ++n) {
        const float xv = xs[bl][i_loc][n];
        acc.x = fmaf(Wr[n].x, xv, acc.x);
        acc.y = fmaf(Wr[n].y, xv, acc.y);
        acc.z = fmaf(Wr[n].z, xv, acc.z);
        acc.w = fmaf(Wr[n].w, xv, acc.w);
      }
      // lanes of a wave write 4*l..4*l+3 -> one contiguous 1KB store per wave
      *reinterpret_cast<float4*>(
          hat + (((size_t)b * NUM_CAPS + j) * IN_CAPS + i) * DIM_CAPS + m0) = acc;
    }
    __syncthreads();
  }
}

// ---------------------------------------------------------------------------
// Kernel B: full 3-iteration routing for one (b, j); hat slice LDS-resident,
// stored transposed hs[m][i] so per-thread 4-consecutive-i reads are b128.
// 512 threads; thread t owns i in {4t..4t+3}; logits live in registers.
// ---------------------------------------------------------------------------
__global__ __launch_bounds__(512) void caps_route_kernel(
    const float* __restrict__ hat, float* __restrict__ out)
{
  __shared__ float hs[DIM_CAPS][IN_CAPS];  // 128 KiB, [m][i]
  __shared__ float red[8][16];
  __shared__ float outs[16];
  __shared__ float sred[8];

  const int bid  = blockIdx.x;
  const int b    = bid >> 5;
  const int j    = bid & 31;
  const int t    = threadIdx.x;
  const int lane = t & 63;
  const int wv   = t >> 6;

  const float* hbase = hat + ((size_t)b * NUM_CAPS + j) * (IN_CAPS * DIM_CAPS);
#pragma unroll
  for (int k = 0; k < 16; ++k) {
    const int u  = t + k * 512;     // float4 index within 128KB slice
    const int i  = u >> 2;
    const int m0 = (u & 3) * 4;
    float4 v = *reinterpret_cast<const float4*>(hbase + (size_t)u * 4);
    hs[m0 + 0][i] = v.x;
    hs[m0 + 1][i] = v.y;
    hs[m0 + 2][i] = v.z;
    hs[m0 + 3][i] = v.w;
  }
  __syncthreads();

  const int i0 = t * 4;
  float lg0 = 0.f, lg1 = 0.f, lg2 = 0.f, lg3 = 0.f;

  for (int r = 0; r < NROUTE; ++r) {
    float c0, c1, c2, c3;
    if (r == 0) {
      c0 = c1 = c2 = c3 = 1.0f / IN_CAPS;   // softmax of zeros
    } else {
      // block softmax over 2048 logits (4 per thread, in regs)
      float mx = fmaxf(fmaxf(lg0, lg1), fmaxf(lg2, lg3));
#pragma unroll
      for (int off = 32; off >= 1; off >>= 1)
        mx = fmaxf(mx, __shfl_xor(mx, off));
      if (lane == 0) sred[wv] = mx;
      __syncthreads();
      float bm = sred[0];
#pragma unroll
      for (int w2 = 1; w2 < 8; ++w2) bm = fmaxf(bm, sred[w2]);
      const float e0 = expf(lg0 - bm), e1 = expf(lg1 - bm);
      const float e2 = expf(lg2 - bm), e3 = expf(lg3 - bm);
      float se = e0 + e1 + e2 + e3;
#pragma unroll
      for (int off = 32; off >= 1; off >>= 1) se += __shfl_xor(se, off);
      __syncthreads();                 // all done reading sred (max phase)
      if (lane == 0) sred[wv] = se;
      __syncthreads();
      float bs = 0.f;
#pragma unroll
      for (int w2 = 0; w2 < 8; ++w2) bs += sred[w2];
      const float inv = 1.0f / bs;
      c0 = e0 * inv; c1 = e1 * inv; c2 = e2 * inv; c3 = e3 * inv;
    }

    // s[m] = sum_i c_i * hat[i][m]  (per-thread partial over 4 i's)
    float acc[16];
#pragma unroll
    for (int m = 0; m < 16; ++m) {
      const float4 h = *reinterpret_cast<const float4*>(&hs[m][i0]);
      acc[m] = c0 * h.x + c1 * h.y + c2 * h.z + c3 * h.w;
    }
#pragma unroll
    for (int m = 0; m < 16; ++m) {
      float a = acc[m];
#pragma unroll
      for (int off = 32; off >= 1; off >>= 1) a += __shfl_xor(a, off);
      acc[m] = a;
    }
    if (lane == 0) {
#pragma unroll
      for (int m = 0; m < 16; ++m) red[wv][m] = acc[m];
    }
    __syncthreads();
    if (t < 16) {
      float s = 0.f;
#pragma unroll
      for (int w2 = 0; w2 < 8; ++w2) s += red[w2][t];
      float n2 = s * s;                 // squash: norm over the 16 lanes
#pragma unroll
      for (int off = 8; off >= 1; off >>= 1) n2 += __shfl_xor(n2, off);
      const float scale = n2 / (1.0f + n2) * rsqrtf(n2 + CAPS_EPS);
      const float o = scale * s;
      outs[t] = o;
      if (r == NROUTE - 1)
        out[((size_t)b * NUM_CAPS + j) * DIM_CAPS + t] = o;
    }
    __syncthreads();

    if (r < NROUTE - 1) {
      // logit update: lg_i += sum_m outs[m] * hat[i][m]
      float d0 = 0.f, d1 = 0.f, d2 = 0.f, d3 = 0.f;
#pragma unroll
      for (int m = 0; m < 16; ++m) {
        const float om = outs[m];
        const float4 h = *reinterpret_cast<const float4*>(&hs[m][i0]);
        d0 = fmaf(om, h.x, d0);
        d1 = fmaf(om, h.y, d1);
        d2 = fmaf(om, h.z, d2);
        d3 = fmaf(om, h.w, d3);
      }
      lg0 += d0; lg1 += d1; lg2 += d2; lg3 += d3;
    }
  }
}

extern "C" void kernel_launch(void* const* d_in, const int* in_sizes, int n_in,
                              void* d_out, int out_size, void* d_ws, size_t ws_size,
                              hipStream_t stream) {
  (void)in_sizes; (void)n_in; (void)out_size; (void)ws_size;
  const float* x = (const float*)d_in[0];   // [64][2048][16]
  const float* W = (const float*)d_in[1];   // [2048][32][16][16]
  float* outp = (float*)d_out;              // [64][32][16]
  float* hat  = (float*)d_ws;               // [64][32][2048][16] = 256 MB

  caps_hat_kernel<<<dim3(1024), dim3(256), 0, stream>>>(x, W, hat);
  caps_route_kernel<<<dim3(2048), dim3(512), 0, stream>>>(hat, outp);
}

// Round 2
// 79.029 us; speedup vs baseline: 2.6944x; 2.6944x over previous
//
#include <hip/hip_runtime.h>
#include <hip/hip_fp16.h>
#include <math.h>

#define BATCH    64
#define IN_CAPS  2048
#define IN_DIM   16
#define NUM_CAPS 32
#define DIM_CAPS 16
#define NROUTE   3
#define CAPS_EPS 1e-7f

typedef unsigned short ushort_t;

// ---------------------------------------------------------------------------
// Kernel A: hat[b][j][i][m] = sum_n W[i][j][n][m] * x[b][i][n]   (fp16 out)
// grid 1024 = 128 i-groups x 8 j-groups; 256 threads = 4 waves (wave w -> j)
// Each lane holds W[i, j, :, m0:m0+4] in 16 float4 regs; loops all 64 b.
// ---------------------------------------------------------------------------
__global__ __launch_bounds__(256) void caps_hat_kernel(
    const float* __restrict__ x, const float* __restrict__ W,
    ushort_t* __restrict__ hat)
{
  const int bid   = blockIdx.x;
  const int ig    = bid & 127;     // i-group of 16
  const int jb    = bid >> 7;      // 0..7
  const int t     = threadIdx.x;
  const int wv    = t >> 6;        // wave 0..3
  const int l     = t & 63;
  const int j     = jb * 4 + wv;
  const int i_loc = l >> 2;
  const int m0    = (l & 3) * 4;
  const int i     = ig * 16 + i_loc;

  float4 Wr[16];
  {
    const float* wbase = W + (((size_t)i * NUM_CAPS + j) * IN_DIM) * DIM_CAPS + m0;
#pragma unroll
    for (int n = 0; n < 16; ++n)
      Wr[n] = *reinterpret_cast<const float4*>(wbase + n * DIM_CAPS);
  }

  __shared__ float xs[16][16][17];   // [b_loc][i_loc][n], pad 17: conflict-free

  for (int bc = 0; bc < 4; ++bc) {
    const int b0 = bc * 16;
#pragma unroll
    for (int k = 0; k < 4; ++k) {
      const int u   = t + k * 256;
      const int bl  = u >> 6;
      const int rem = u & 63;
      const int il  = rem >> 2;
      const int n0  = (rem & 3) * 4;
      float4 v = *reinterpret_cast<const float4*>(
          x + ((size_t)(b0 + bl) * IN_CAPS + ig * 16 + il) * IN_DIM + n0);
      xs[bl][il][n0 + 0] = v.x;
      xs[bl][il][n0 + 1] = v.y;
      xs[bl][il][n0 + 2] = v.z;
      xs[bl][il][n0 + 3] = v.w;
    }
    __syncthreads();
#pragma unroll
    for (int bl = 0; bl < 16; ++bl) {
      const int b = b0 + bl;
      float4 acc = make_float4(0.f, 0.f, 0.f, 0.f);
#pragma unroll
      for (int n = 0; n < 16; ++n) {
        const float xv = xs[bl][i_loc][n];
        acc.x = fmaf(Wr[n].x, xv, acc.x);
        acc.y = fmaf(Wr[n].y, xv, acc.y);
        acc.z = fmaf(Wr[n].z, xv, acc.z);
        acc.w = fmaf(Wr[n].w, xv, acc.w);
      }
      ushort4 st;
      st.x = __half_as_ushort(__float2half(acc.x));
      st.y = __half_as_ushort(__float2half(acc.y));
      st.z = __half_as_ushort(__float2half(acc.z));
      st.w = __half_as_ushort(__float2half(acc.w));
      *reinterpret_cast<ushort4*>(
          hat + (((size_t)b * NUM_CAPS + j) * IN_CAPS + i) * DIM_CAPS + m0) = st;
    }
    __syncthreads();
  }
}

// ---------------------------------------------------------------------------
// Kernel B: 3-iteration routing for one (b,j). hat slice held in REGISTERS:
// 512 threads; chunk u = t + 512q (16B, coalesced). Pair (t, t^1) shares the
// 8 capsules i = (t>>1) + 256q; even lane holds m 0..7, odd lane m 8..15.
// Block reduction: split-butterfly (9 shfl for 8 values), m = f(lane bits).
// ---------------------------------------------------------------------------
__global__ __launch_bounds__(512) void caps_route_kernel(
    const ushort_t* __restrict__ hat, float* __restrict__ out)
{
  __shared__ float red[8][20];   // [wave][m(16) + E(1) + pad]
  __shared__ float outs[16];

  const int bid  = blockIdx.x;            // = b*32 + j
  const int t    = threadIdx.x;
  const int lane = t & 63;
  const int wv   = t >> 6;
  const int mh   = t & 1;                 // m-half: 0 -> m 0..7, 1 -> m 8..15

  const ushort_t* base = hat + (size_t)bid * (IN_CAPS * DIM_CAPS);

  uint4 g[8];
#pragma unroll
  for (int q = 0; q < 8; ++q)
    g[q] = *reinterpret_cast<const uint4*>(base + (size_t)(t + 512 * q) * 8);

  // H(q,s): fp16 value of hat[i_q][8*mh + s]
#define HVAL(q, s) __half2float(__ushort_as_half((ushort_t)( \
    ((s) & 1) ? (((const unsigned int*)&g[(q)])[(s) >> 1] >> 16) \
              : (((const unsigned int*)&g[(q)])[(s) >> 1] & 0xffffu))))

  const int b1 = (lane >> 1) & 1;
  const int b2 = (lane >> 2) & 1;
  const int b3 = (lane >> 3) & 1;
  // final m index this lane's butterfly result represents
  const int m_fin = 8 * mh + 4 * b3 + 2 * b2 + b1;

  float lg[8];
#pragma unroll
  for (int q = 0; q < 8; ++q) lg[q] = 0.f;

  for (int r = 0; r < NROUTE; ++r) {
    float e[8];
    float Ep = 0.f;
    if (r == 0) {
#pragma unroll
      for (int q = 0; q < 8; ++q) e[q] = 1.f;
    } else {
#pragma unroll
      for (int q = 0; q < 8; ++q) { e[q] = __expf(lg[q]); Ep += e[q]; }
    }

    // acc[s] = sum over my 8 i's of e_i * hat[i][8*mh+s]
    float acc[8];
#pragma unroll
    for (int s = 0; s < 8; ++s) {
      float a = 0.f;
#pragma unroll
      for (int q = 0; q < 8; ++q) a = fmaf(e[q], HVAL(q, s), a);
      acc[s] = a;
    }

    // ---- split-butterfly reduction over the wave (m-half already on bit0)
    float v4[4];
#pragma unroll
    for (int k = 0; k < 4; ++k) {               // xor 2  <-> s bit0
      float send = b1 ? acc[2 * k] : acc[2 * k + 1];
      float recv = __shfl_xor(send, 2);
      float keep = b1 ? acc[2 * k + 1] : acc[2 * k];
      v4[k] = keep + recv;                      // s = 2k + b1
    }
    float v2[2];
#pragma unroll
    for (int k = 0; k < 2; ++k) {               // xor 4  <-> s bit1
      float send = b2 ? v4[2 * k] : v4[2 * k + 1];
      float recv = __shfl_xor(send, 4);
      float keep = b2 ? v4[2 * k + 1] : v4[2 * k];
      v2[k] = keep + recv;                      // s = 4k + 2*b2 + b1
    }
    float z;
    {                                           // xor 8  <-> s bit2
      float send = b3 ? v2[0] : v2[1];
      float recv = __shfl_xor(send, 8);
      float keep = b3 ? v2[1] : v2[0];
      z = keep + recv;                          // s = 4*b3 + 2*b2 + b1
    }
    z += __shfl_xor(z, 16);
    z += __shfl_xor(z, 32);                     // summed over whole wave

    if (r > 0) {                                // E over wave: bits 1..5 only
      Ep += __shfl_xor(Ep, 2);
      Ep += __shfl_xor(Ep, 4);
      Ep += __shfl_xor(Ep, 8);
      Ep += __shfl_xor(Ep, 16);
      Ep += __shfl_xor(Ep, 32);
      if (lane == 16) red[wv][16] = Ep;
    }
    if (lane < 16) red[wv][m_fin] = z;
    __syncthreads();

    if (t < 16) {
      float s = 0.f;
#pragma unroll
      for (int w = 0; w < 8; ++w) s += red[w][t];
      float E;
      if (r == 0) E = (float)IN_CAPS;
      else {
        E = 0.f;
#pragma unroll
        for (int w = 0; w < 8; ++w) E += red[w][16];
      }
      float sm = s / E;
      float n2 = sm * sm;
#pragma unroll
      for (int off = 8; off >= 1; off >>= 1) n2 += __shfl_xor(n2, off);
      const float scale = n2 / (1.0f + n2) * rsqrtf(n2 + CAPS_EPS);
      const float o = scale * sm;
      outs[t] = o;
      if (r == NROUTE - 1)
        out[(size_t)bid * DIM_CAPS + t] = o;
    }
    __syncthreads();

    if (r < NROUTE - 1) {
      // logit update: lg_i += sum_m outs[m]*hat[i][m]; my half + partner half
#pragma unroll
      for (int q = 0; q < 8; ++q) {
        float d = 0.f;
#pragma unroll
        for (int s = 0; s < 8; ++s) d = fmaf(outs[8 * mh + s], HVAL(q, s), d);
        d += __shfl_xor(d, 1);                  // add partner's m-half
        lg[q] += d;
      }
    }
  }
#undef HVAL
}

extern "C" void kernel_launch(void* const* d_in, const int* in_sizes, int n_in,
                              void* d_out, int out_size, void* d_ws, size_t ws_size,
                              hipStream_t stream) {
  (void)in_sizes; (void)n_in; (void)out_size; (void)ws_size;
  const float* x = (const float*)d_in[0];      // [64][2048][16]
  const float* W = (const float*)d_in[1];      // [2048][32][16][16]
  float* outp = (float*)d_out;                 // [64][32][16]
  ushort_t* hat = (ushort_t*)d_ws;             // [64][32][2048][16] fp16 = 128 MB

  caps_hat_kernel<<<dim3(1024), dim3(256), 0, stream>>>(x, W, hat);
  caps_route_kernel<<<dim3(BATCH * NUM_CAPS), dim3(512), 0, stream>>>(hat, outp);
}